// Round 8
// baseline (8325.125 us; speedup 1.0000x reference)
//
#include <hip/hip_runtime.h>
#include <hip/hip_bf16.h>
#include <stdint.h>

#define T_TOK 8192
#define HID   2048
#define FFN   1024
#define NEXP  64
#define ETOT  72
#define NPAD  80
#define TOPK  8
#define NASSIGN (T_TOK*TOPK)

typedef unsigned short u16;
typedef __bf16 bf16;
typedef bf16 bf16x8 __attribute__((ext_vector_type(8)));
typedef float f32x4 __attribute__((ext_vector_type(4)));

typedef const __attribute__((address_space(1))) void* gp_t;
typedef __attribute__((address_space(3))) void* lp_t;

__device__ __forceinline__ void gload16(const void* g, void* lds) {
  __builtin_amdgcn_global_load_lds((gp_t)g, (lp_t)lds, 16, 0, 0);
}
__device__ __forceinline__ f32x4 mfma16(bf16x8 a, bf16x8 b, f32x4 c) {
  return __builtin_amdgcn_mfma_f32_16x16x32_bf16(a, b, c, 0, 0, 0);
}

union U8 { bf16 h[8]; uint4 u; };
union U2 { bf16 h[2]; unsigned int u; };

// ---------------- K0: fp32 -> bf16 hi/lo split of x ----------------
__global__ void k_prep_x(const float* __restrict__ x, u16* __restrict__ xh,
                         u16* __restrict__ xl, int n8) {
  int i = blockIdx.x * blockDim.x + threadIdx.x;
  int stride = gridDim.x * blockDim.x;
  for (; i < n8; i += stride) {
    const float4* p = (const float4*)(x + (size_t)i * 8);
    float4 a = p[0], b = p[1];
    float f[8] = {a.x,a.y,a.z,a.w,b.x,b.y,b.z,b.w};
    U8 hh, ll;
#pragma unroll
    for (int j = 0; j < 8; j++) {
      bf16 h = (bf16)f[j];
      hh.h[j] = h;
      ll.h[j] = (bf16)(f[j] - (float)h);
    }
    ((uint4*)xh)[i] = hh.u;
    ((uint4*)xl)[i] = ll.u;
  }
}

// ---------------- K0b: gate_w -> bf16 hi/lo, padded to 80 rows ----------------
__global__ void k_prep_gate(const float* __restrict__ gw, u16* __restrict__ gh,
                            u16* __restrict__ gl) {
  int e = blockIdx.x;
  for (int k8 = threadIdx.x; k8 < HID/8; k8 += blockDim.x) {
    U8 hh, ll;
    if (e < ETOT) {
      const float4* p = (const float4*)(gw + (size_t)e*HID + k8*8);
      float4 a = p[0], b = p[1];
      float f[8] = {a.x,a.y,a.z,a.w,b.x,b.y,b.z,b.w};
#pragma unroll
      for (int j = 0; j < 8; j++) {
        bf16 h = (bf16)f[j]; hh.h[j] = h; ll.h[j] = (bf16)(f[j]-(float)h);
      }
    } else {
      hh.u = make_uint4(0,0,0,0); ll.u = make_uint4(0,0,0,0);
    }
    ((uint4*)gh)[(size_t)e*(HID/8) + k8] = hh.u;
    ((uint4*)gl)[(size_t)e*(HID/8) + k8] = ll.u;
  }
}

// ---------------- K0c: fp32 [R][C] -> bf16 [C][R] transpose-convert ----------------
__global__ void k_convT(const float* __restrict__ src, u16* __restrict__ dst,
                        int R, int C) {
  int e = blockIdx.z;
  src += (size_t)e * R * C;
  dst += (size_t)e * R * C;
  int c0 = blockIdx.x * 64, r0 = blockIdx.y * 128;
  __shared__ u16 t[64 * 132];
  int tid = threadIdx.x;
  int rr = tid >> 4, cc = (tid & 15) * 4;
#pragma unroll
  for (int it = 0; it < 8; it++) {
    int r = it * 16 + rr;
    float4 v = *(const float4*)(src + (size_t)(r0 + r) * C + c0 + cc);
    const float* f = &v.x;
#pragma unroll
    for (int i = 0; i < 4; i++) {
      U2 u; u.h[0] = (bf16)f[i]; u.h[1] = (bf16)0.f;
      t[(cc + i) * 132 + r] = (u16)(u.u & 0xffffu);
    }
  }
  __syncthreads();
  int n = tid >> 2, kb = (tid & 3) * 32;
  u16* drow = dst + (size_t)(c0 + n) * R + r0 + kb;
  const u16* srow = &t[n * 132 + kb];
#pragma unroll
  for (int j = 0; j < 2; j++) {
    uint2 a = *(const uint2*)&srow[j*16 + 0];
    uint2 b = *(const uint2*)&srow[j*16 + 4];
    uint2 c = *(const uint2*)&srow[j*16 + 8];
    uint2 d = *(const uint2*)&srow[j*16 + 12];
    *(uint4*)&drow[j*16]     = make_uint4(a.x, a.y, b.x, b.y);
    *(uint4*)&drow[j*16 + 8] = make_uint4(c.x, c.y, d.x, d.y);
  }
}

// ---------------- K1: router ----------------
__global__ void k_router(const u16* __restrict__ xh, const u16* __restrict__ xl,
                         const u16* __restrict__ gh, const u16* __restrict__ gl,
                         float* __restrict__ logits_out, int* __restrict__ tk_idx,
                         float* __restrict__ tk_w, int* __restrict__ counts) {
  __shared__ u16 la_h[64*32], la_l[64*32], lb_h[NPAD*32], lb_l[NPAD*32];
  __shared__ float llog[64*NPAD];
  int tid = threadIdx.x, lane = tid & 63, wid = tid >> 6;
  int t0 = blockIdx.x * 64;
  int rsub = lane >> 2, csub = lane & 3;
  f32x4 acc[5] = {};
#pragma unroll 1
  for (int k0 = 0; k0 < HID; k0 += 32) {
    int arow = wid*16 + rsub;
    gload16(xh + (size_t)(t0+arow)*HID + k0 + csub*8, &la_h[wid*512]);
    gload16(xl + (size_t)(t0+arow)*HID + k0 + csub*8, &la_l[wid*512]);
    int brow = wid*16 + rsub;
    gload16(gh + (size_t)brow*HID + k0 + csub*8, &lb_h[wid*512]);
    gload16(gl + (size_t)brow*HID + k0 + csub*8, &lb_l[wid*512]);
    if (wid == 0) gload16(gh + (size_t)(64+rsub)*HID + k0 + csub*8, &lb_h[4*512]);
    if (wid == 1) gload16(gl + (size_t)(64+rsub)*HID + k0 + csub*8, &lb_l[4*512]);
    __syncthreads();
    int ar = wid*16 + (lane & 15);
    int ks = lane >> 4;
    bf16x8 ah = *(const bf16x8*)&la_h[ar*32 + ks*8];
    bf16x8 al = *(const bf16x8*)&la_l[ar*32 + ks*8];
#pragma unroll
    for (int nf = 0; nf < 5; nf++) {
      int br = nf*16 + (lane & 15);
      bf16x8 bh = *(const bf16x8*)&lb_h[br*32 + ks*8];
      bf16x8 bl = *(const bf16x8*)&lb_l[br*32 + ks*8];
      acc[nf] = mfma16(ah, bh, acc[nf]);
      acc[nf] = mfma16(ah, bl, acc[nf]);
      acc[nf] = mfma16(al, bh, acc[nf]);
    }
    __syncthreads();
  }
  {
    int q = lane >> 4, c = lane & 15;
#pragma unroll
    for (int nf = 0; nf < 5; nf++)
#pragma unroll
      for (int r = 0; r < 4; r++)
        llog[(wid*16 + q*4 + r)*NPAD + nf*16 + c] = acc[nf][r];
  }
  __syncthreads();
  if (tid < 64) {
    int t = t0 + tid;
    float* lg = &llog[tid*NPAD];
    float m = -1e30f;
    for (int e = 0; e < ETOT; e++) {
      float v = lg[e];
      logits_out[(size_t)t*ETOT + e] = v;
      m = fmaxf(m, v);
    }
    float s = 0.f;
    for (int e = 0; e < ETOT; e++) s += __expf(lg[e] - m);
    uint64_t m0 = 0; unsigned int m1 = 0;
    for (int k = 0; k < TOPK; k++) {
      float best = -1e30f; int bi = 0;
      for (int e = 0; e < ETOT; e++) {
        bool used = (e < 64) ? ((m0 >> e) & 1) : ((m1 >> (e-64)) & 1);
        float v = lg[e];
        if (!used && v > best) { best = v; bi = e; }
      }
      if (bi < 64) m0 |= (1ull << bi); else m1 |= (1u << (bi-64));
      tk_idx[t*TOPK + k] = bi;
      tk_w[t*TOPK + k] = __expf(best - m) / s;
      if (bi < NEXP) atomicAdd(&counts[bi], 1);
    }
  }
}

// ---------------- K2: scan ----------------
__global__ void k_scan(const int* __restrict__ counts, int* __restrict__ offsets,
                       int* __restrict__ cursors) {
  if (threadIdx.x == 0) {
    int s = 0;
    for (int e = 0; e < NEXP; e++) { offsets[e] = s; cursors[e] = s; s += counts[e]; }
  }
}

// ---------------- K3: build grouped lists ----------------
__global__ void k_build(const int* __restrict__ tk_idx, const float* __restrict__ tk_w,
                        int* __restrict__ cursors, int* __restrict__ rows,
                        float* __restrict__ rwgt) {
  int t = blockIdx.x * blockDim.x + threadIdx.x;
  if (t >= T_TOK) return;
#pragma unroll
  for (int k = 0; k < TOPK; k++) {
    int e = tk_idx[t*TOPK + k];
    if (e < NEXP) {
      int p = atomicAdd(&cursors[e], 1);
      rows[p] = t;
      rwgt[p] = tk_w[t*TOPK + k];
    }
  }
}

// ---------------- K4: grouped gate/up GEMM (bf16 [n][k] weights) --------------
// Round-6 lockstep structure (stage -> sync -> compute -> sync): the shared
// load-rate limit keeps the 8 m-blocks of a group in lockstep -> L2/L3 dedup
// (round 7 proved prefetch breaks this: FETCH 0.57->1.58 GB). Delta vs r6:
// LDS 40->24 KB (epilogue lout overlays la/lbg after final barrier) ->
// 5 blocks/CU; independent blocks hide each other's barrier drains (m114).
__launch_bounds__(256, 5)
__global__ void k_expert_gu(const u16* __restrict__ xh, const u16* __restrict__ wgT,
                            const u16* __restrict__ wuT, const int* __restrict__ counts,
                            const int* __restrict__ offsets, const int* __restrict__ rows,
                            u16* __restrict__ inter) {
  int wgid = blockIdx.x;
  int xcd = wgid & 7, slot = wgid >> 3;   // 512 slots per XCD
  int m = slot & 7, q = slot >> 3;        // q = 0..63
  int g = xcd * 64 + q;                   // group 0..511
  int e = g >> 3, nb = g & 7;
  int cnt = counts[e];
  if (cnt == 0) return;
  int off = offsets[e];
  int n0 = nb * 128;
  int tid = threadIdx.x, lane = tid & 63, wid = tid >> 6;
  int wm = (wid >> 1) * 64, wn = (wid & 1) * 64;
  __shared__ __align__(16) char smem[24576];
  u16* la  = (u16*)smem;                // [128*32]
  u16* lbg = (u16*)(smem + 8192);       // [128*32]
  u16* lbu = (u16*)(smem + 16384);      // [128*32]
  u16* lout = (u16*)smem;               // epilogue overlay [64][128] (16 KB)
  int rsub = lane >> 2, csub = lane & 3;
  int swzc = csub ^ ((rsub >> 1) & 3);
  int nr1 = wid*16 + rsub, nr2 = nr1 + 64;
  const u16* gb_g1 = wgT + ((size_t)e*FFN + n0 + nr1)*HID + swzc*8;
  const u16* gb_g2 = wgT + ((size_t)e*FFN + n0 + nr2)*HID + swzc*8;
  const u16* gb_u1 = wuT + ((size_t)e*FFN + n0 + nr1)*HID + swzc*8;
  const u16* gb_u2 = wuT + ((size_t)e*FFN + n0 + nr2)*HID + swzc*8;

  for (int m0 = m * 128; m0 < cnt; m0 += 1024) {
    int tok1 = (m0 + nr1 < cnt) ? rows[off + m0 + nr1] : 0;
    int tok2 = (m0 + nr2 < cnt) ? rows[off + m0 + nr2] : 0;
    const u16* ga1 = xh + (size_t)tok1*HID + swzc*8;
    const u16* ga2 = xh + (size_t)tok2*HID + swzc*8;
    f32x4 accg[4][4] = {}, accu[4][4] = {};
#pragma unroll 1
    for (int k0 = 0; k0 < HID; k0 += 32) {
      gload16(ga1 + k0, &la[wid*512]);
      gload16(ga2 + k0, &la[(wid+4)*512]);
      gload16(gb_g1 + k0, &lbg[wid*512]);
      gload16(gb_g2 + k0, &lbg[(wid+4)*512]);
      gload16(gb_u1 + k0, &lbu[wid*512]);
      gload16(gb_u2 + k0, &lbu[(wid+4)*512]);
      __syncthreads();
      bf16x8 afr[4], bgf[4], buf_[4];
#pragma unroll
      for (int i = 0; i < 4; i++) {
        int row = wm + i*16 + (lane & 15);
        int ch = (lane >> 4) ^ ((row >> 1) & 3);
        afr[i] = *(const bf16x8*)&la[row*32 + ch*8];
        int n = wn + i*16 + (lane & 15);
        int chb = (lane >> 4) ^ ((n >> 1) & 3);
        bgf[i]  = *(const bf16x8*)&lbg[n*32 + chb*8];
        buf_[i] = *(const bf16x8*)&lbu[n*32 + chb*8];
      }
#pragma unroll
      for (int nf = 0; nf < 4; nf++)
#pragma unroll
        for (int mf = 0; mf < 4; mf++) {
          accg[mf][nf] = mfma16(afr[mf], bgf[nf], accg[mf][nf]);
          accu[mf][nf] = mfma16(afr[mf], buf_[nf], accu[mf][nf]);
        }
      __syncthreads();
    }
    // epilogue: silu(g)*u, two 64-row passes through lout overlay
#pragma unroll
    for (int pass = 0; pass < 2; pass++) {
      if ((wid >> 1) == pass) {
#pragma unroll
        for (int mf = 0; mf < 4; mf++)
#pragma unroll
          for (int nf = 0; nf < 4; nf++)
#pragma unroll
            for (int r = 0; r < 4; r++) {
              float gg = accg[mf][nf][r], uu = accu[mf][nf][r];
              float v = gg / (1.f + __expf(-gg)) * uu;
              int row = mf*16 + (lane >> 4)*4 + r;      // 0..63 local
              int col = wn + nf*16 + (lane & 15);
              U2 t; t.h[0] = (bf16)v; t.h[1] = (bf16)0.f;
              lout[row*128 + col] = (u16)(t.u & 0xffffu);
            }
      }
      __syncthreads();
      for (int idx = tid; idx < 1024; idx += 256) {
        int row = idx >> 4, c16 = idx & 15;
        int grow = m0 + pass*64 + row;
        if (grow < cnt) {
          uint4 v = *(const uint4*)&lout[row*128 + c16*8];
          *(uint4*)&inter[(size_t)(off + grow)*FFN + n0 + c16*8] = v;
        }
      }
      __syncthreads();
    }
  }
}

// ---------------- K5: grouped down GEMM (bf16 wdT), atomic scatter-add --------
// Round-6 lockstep structure; 16.5 KB LDS; 5 blocks/CU.
__launch_bounds__(256, 5)
__global__ void k_expert_down(const u16* __restrict__ inter, const u16* __restrict__ wdT,
                              const int* __restrict__ counts, const int* __restrict__ offsets,
                              const int* __restrict__ rows, const float* __restrict__ rwgt,
                              float* __restrict__ out) {
  int wgid = blockIdx.x;
  int xcd = wgid & 7, slot = wgid >> 3;   // 512 slots per XCD
  int m = slot & 3, q = slot >> 2;        // q = 0..127
  int g = xcd * 128 + q;                  // group 0..1023
  int e = g >> 4, nb = g & 15;
  int cnt = counts[e];
  if (cnt == 0) return;
  int off = offsets[e];
  int n0 = nb * 128;
  int tid = threadIdx.x, lane = tid & 63, wid = tid >> 6;
  int wm = (wid >> 1) * 64, wn = (wid & 1) * 64;
  __shared__ u16 la[128*32], lb[128*32];
  __shared__ int rows_l[128];
  __shared__ float rw_l[128];
  int rsub = lane >> 2, csub = lane & 3;
  int swzc = csub ^ ((rsub >> 1) & 3);
  int nr1 = wid*16 + rsub, nr2 = nr1 + 64;
  const u16* gb1 = wdT + ((size_t)e*HID + n0 + nr1)*FFN + swzc*8;
  const u16* gb2 = wdT + ((size_t)e*HID + n0 + nr2)*FFN + swzc*8;

  for (int m0 = m * 128; m0 < cnt; m0 += 512) {
    __syncthreads();
    if (tid < 128) {
      int r = m0 + tid;
      rows_l[tid] = (r < cnt) ? rows[off + r] : 0;
      rw_l[tid]   = (r < cnt) ? rwgt[off + r] : 0.f;
    }
    const u16* ga1 = inter + (size_t)(off + m0 + nr1)*FFN + swzc*8;
    const u16* ga2 = inter + (size_t)(off + m0 + nr2)*FFN + swzc*8;
    f32x4 acc[4][4] = {};
#pragma unroll 1
    for (int k0 = 0; k0 < FFN; k0 += 32) {
      gload16(ga1 + k0, &la[wid*512]);
      gload16(ga2 + k0, &la[(wid+4)*512]);
      gload16(gb1 + k0, &lb[wid*512]);
      gload16(gb2 + k0, &lb[(wid+4)*512]);
      __syncthreads();
      bf16x8 afr[4], bfr[4];
#pragma unroll
      for (int i = 0; i < 4; i++) {
        int row = wm + i*16 + (lane & 15);
        int ch = (lane >> 4) ^ ((row >> 1) & 3);
        afr[i] = *(const bf16x8*)&la[row*32 + ch*8];
        int n = wn + i*16 + (lane & 15);
        int chb = (lane >> 4) ^ ((n >> 1) & 3);
        bfr[i] = *(const bf16x8*)&lb[n*32 + chb*8];
      }
#pragma unroll
      for (int nf = 0; nf < 4; nf++)
#pragma unroll
        for (int mf = 0; mf < 4; mf++)
          acc[mf][nf] = mfma16(afr[mf], bfr[nf], acc[mf][nf]);
      __syncthreads();
    }
#pragma unroll
    for (int mf = 0; mf < 4; mf++)
#pragma unroll
      for (int nf = 0; nf < 4; nf++)
#pragma unroll
        for (int r = 0; r < 4; r++) {
          int row = wm + mf*16 + (lane >> 4)*4 + r;
          if (m0 + row < cnt) {
            int tok = rows_l[row];
            float w = rw_l[row];
            int col = n0 + wn + nf*16 + (lane & 15);
            atomicAdd(&out[(size_t)tok*HID + col], w * acc[mf][nf][r]);
          }
        }
  }
}

// ---------------- launch ----------------
extern "C" void kernel_launch(void* const* d_in, const int* in_sizes, int n_in,
                              void* d_out, int out_size, void* d_ws, size_t ws_size,
                              hipStream_t stream) {
  const float* x      = (const float*)d_in[0];
  const float* gate_w = (const float*)d_in[1];
  const float* wg     = (const float*)d_in[2];
  const float* wu     = (const float*)d_in[3];
  const float* wd     = (const float*)d_in[4];
  float* out = (float*)d_out;
  float* logits_out = out + (size_t)T_TOK * HID;

  char* w = (char*)d_ws;
  u16* xh = (u16*)w;            w += (size_t)T_TOK*HID*2;
  u16* xl = (u16*)w;            w += (size_t)T_TOK*HID*2;
  u16* gh = (u16*)w;            w += (size_t)NPAD*HID*2;
  u16* gl = (u16*)w;            w += (size_t)NPAD*HID*2;
  int* tk_idx = (int*)w;        w += (size_t)T_TOK*TOPK*4;
  float* tk_w = (float*)w;      w += (size_t)T_TOK*TOPK*4;
  int* counts = (int*)w;        w += 256;
  int* offsets = (int*)w;       w += 256;
  int* cursors = (int*)w;       w += 256;
  int* rows = (int*)w;          w += (size_t)NASSIGN*4;
  float* rwgt = (float*)w;      w += (size_t)NASSIGN*4;
  u16* inter = (u16*)w;         w += ((size_t)NASSIGN + 256)*FFN*2;
  u16* wgT = (u16*)w;           w += (size_t)NEXP*FFN*HID*2;
  u16* wuT = (u16*)w;           w += (size_t)NEXP*FFN*HID*2;
  u16* wdT = (u16*)w;           // NEXP*HID*FFN*2

  hipMemsetAsync(d_out, 0, (size_t)T_TOK*HID*4, stream);
  hipMemsetAsync(counts, 0, 256, stream);

  k_prep_x<<<2048, 256, 0, stream>>>(x, xh, xl, T_TOK*HID/8);
  k_prep_gate<<<NPAD, 256, 0, stream>>>(gate_w, gh, gl);
  k_router<<<T_TOK/64, 256, 0, stream>>>(xh, xl, gh, gl, logits_out, tk_idx, tk_w, counts);
  k_scan<<<1, 64, 0, stream>>>(counts, offsets, cursors);
  k_build<<<T_TOK/256, 256, 0, stream>>>(tk_idx, tk_w, cursors, rows, rwgt);

  // one-shot full weight conversion to bf16 [n][k]
  k_convT<<<dim3(FFN/64, HID/128, NEXP), 256, 0, stream>>>(wg, wgT, HID, FFN);
  k_convT<<<dim3(FFN/64, HID/128, NEXP), 256, 0, stream>>>(wu, wuT, HID, FFN);
  k_convT<<<dim3(HID/64, FFN/128, NEXP), 256, 0, stream>>>(wd, wdT, FFN, HID);

  k_expert_gu<<<4096, 256, 0, stream>>>(xh, wgT, wuT, counts, offsets, rows, inter);
  k_expert_down<<<4096, 256, 0, stream>>>(inter, wdT, counts, offsets, rows, rwgt, out);
}

// Round 9
// 4846.686 us; speedup vs baseline: 1.7177x; 1.7177x over previous
//
#include <hip/hip_runtime.h>
#include <hip/hip_bf16.h>
#include <stdint.h>

#define T_TOK 8192
#define HID   2048
#define FFN   1024
#define NEXP  64
#define ETOT  72
#define NPAD  80
#define TOPK  8
#define NASSIGN (T_TOK*TOPK)

typedef unsigned short u16;
typedef __bf16 bf16;
typedef bf16 bf16x8 __attribute__((ext_vector_type(8)));
typedef float f32x4 __attribute__((ext_vector_type(4)));

typedef const __attribute__((address_space(1))) void* gp_t;
typedef __attribute__((address_space(3))) void* lp_t;

__device__ __forceinline__ void gload16(const void* g, void* lds) {
  __builtin_amdgcn_global_load_lds((gp_t)g, (lp_t)lds, 16, 0, 0);
}
__device__ __forceinline__ f32x4 mfma16(bf16x8 a, bf16x8 b, f32x4 c) {
  return __builtin_amdgcn_mfma_f32_16x16x32_bf16(a, b, c, 0, 0, 0);
}

union U8 { bf16 h[8]; uint4 u; };
union U2 { bf16 h[2]; unsigned int u; };

// ---------------- K0: fp32 -> bf16 hi/lo split of x ----------------
__global__ void k_prep_x(const float* __restrict__ x, u16* __restrict__ xh,
                         u16* __restrict__ xl, int n8) {
  int i = blockIdx.x * blockDim.x + threadIdx.x;
  int stride = gridDim.x * blockDim.x;
  for (; i < n8; i += stride) {
    const float4* p = (const float4*)(x + (size_t)i * 8);
    float4 a = p[0], b = p[1];
    float f[8] = {a.x,a.y,a.z,a.w,b.x,b.y,b.z,b.w};
    U8 hh, ll;
#pragma unroll
    for (int j = 0; j < 8; j++) {
      bf16 h = (bf16)f[j];
      hh.h[j] = h;
      ll.h[j] = (bf16)(f[j] - (float)h);
    }
    ((uint4*)xh)[i] = hh.u;
    ((uint4*)xl)[i] = ll.u;
  }
}

// ---------------- K0b: gate_w -> bf16 hi/lo, padded to 80 rows ----------------
__global__ void k_prep_gate(const float* __restrict__ gw, u16* __restrict__ gh,
                            u16* __restrict__ gl) {
  int e = blockIdx.x;
  for (int k8 = threadIdx.x; k8 < HID/8; k8 += blockDim.x) {
    U8 hh, ll;
    if (e < ETOT) {
      const float4* p = (const float4*)(gw + (size_t)e*HID + k8*8);
      float4 a = p[0], b = p[1];
      float f[8] = {a.x,a.y,a.z,a.w,b.x,b.y,b.z,b.w};
#pragma unroll
      for (int j = 0; j < 8; j++) {
        bf16 h = (bf16)f[j]; hh.h[j] = h; ll.h[j] = (bf16)(f[j]-(float)h);
      }
    } else {
      hh.u = make_uint4(0,0,0,0); ll.u = make_uint4(0,0,0,0);
    }
    ((uint4*)gh)[(size_t)e*(HID/8) + k8] = hh.u;
    ((uint4*)gl)[(size_t)e*(HID/8) + k8] = ll.u;
  }
}

// ---------------- K0c: fp32 [R][C] -> bf16 [C][R] transpose-convert ----------------
__global__ void k_convT(const float* __restrict__ src, u16* __restrict__ dst,
                        int R, int C) {
  int e = blockIdx.z;
  src += (size_t)e * R * C;
  dst += (size_t)e * R * C;
  int c0 = blockIdx.x * 64, r0 = blockIdx.y * 128;
  __shared__ u16 t[64 * 132];
  int tid = threadIdx.x;
  int rr = tid >> 4, cc = (tid & 15) * 4;
#pragma unroll
  for (int it = 0; it < 8; it++) {
    int r = it * 16 + rr;
    float4 v = *(const float4*)(src + (size_t)(r0 + r) * C + c0 + cc);
    const float* f = &v.x;
#pragma unroll
    for (int i = 0; i < 4; i++) {
      U2 u; u.h[0] = (bf16)f[i]; u.h[1] = (bf16)0.f;
      t[(cc + i) * 132 + r] = (u16)(u.u & 0xffffu);
    }
  }
  __syncthreads();
  int n = tid >> 2, kb = (tid & 3) * 32;
  u16* drow = dst + (size_t)(c0 + n) * R + r0 + kb;
  const u16* srow = &t[n * 132 + kb];
#pragma unroll
  for (int j = 0; j < 2; j++) {
    uint2 a = *(const uint2*)&srow[j*16 + 0];
    uint2 b = *(const uint2*)&srow[j*16 + 4];
    uint2 c = *(const uint2*)&srow[j*16 + 8];
    uint2 d = *(const uint2*)&srow[j*16 + 12];
    *(uint4*)&drow[j*16]     = make_uint4(a.x, a.y, b.x, b.y);
    *(uint4*)&drow[j*16 + 8] = make_uint4(c.x, c.y, d.x, d.y);
  }
}

// ---------------- K1: router ----------------
__global__ void k_router(const u16* __restrict__ xh, const u16* __restrict__ xl,
                         const u16* __restrict__ gh, const u16* __restrict__ gl,
                         float* __restrict__ logits_out, int* __restrict__ tk_idx,
                         float* __restrict__ tk_w, int* __restrict__ counts) {
  __shared__ u16 la_h[64*32], la_l[64*32], lb_h[NPAD*32], lb_l[NPAD*32];
  __shared__ float llog[64*NPAD];
  int tid = threadIdx.x, lane = tid & 63, wid = tid >> 6;
  int t0 = blockIdx.x * 64;
  int rsub = lane >> 2, csub = lane & 3;
  f32x4 acc[5] = {};
#pragma unroll 1
  for (int k0 = 0; k0 < HID; k0 += 32) {
    int arow = wid*16 + rsub;
    gload16(xh + (size_t)(t0+arow)*HID + k0 + csub*8, &la_h[wid*512]);
    gload16(xl + (size_t)(t0+arow)*HID + k0 + csub*8, &la_l[wid*512]);
    int brow = wid*16 + rsub;
    gload16(gh + (size_t)brow*HID + k0 + csub*8, &lb_h[wid*512]);
    gload16(gl + (size_t)brow*HID + k0 + csub*8, &lb_l[wid*512]);
    if (wid == 0) gload16(gh + (size_t)(64+rsub)*HID + k0 + csub*8, &lb_h[4*512]);
    if (wid == 1) gload16(gl + (size_t)(64+rsub)*HID + k0 + csub*8, &lb_l[4*512]);
    __syncthreads();
    int ar = wid*16 + (lane & 15);
    int ks = lane >> 4;
    bf16x8 ah = *(const bf16x8*)&la_h[ar*32 + ks*8];
    bf16x8 al = *(const bf16x8*)&la_l[ar*32 + ks*8];
#pragma unroll
    for (int nf = 0; nf < 5; nf++) {
      int br = nf*16 + (lane & 15);
      bf16x8 bh = *(const bf16x8*)&lb_h[br*32 + ks*8];
      bf16x8 bl = *(const bf16x8*)&lb_l[br*32 + ks*8];
      acc[nf] = mfma16(ah, bh, acc[nf]);
      acc[nf] = mfma16(ah, bl, acc[nf]);
      acc[nf] = mfma16(al, bh, acc[nf]);
    }
    __syncthreads();
  }
  {
    int q = lane >> 4, c = lane & 15;
#pragma unroll
    for (int nf = 0; nf < 5; nf++)
#pragma unroll
      for (int r = 0; r < 4; r++)
        llog[(wid*16 + q*4 + r)*NPAD + nf*16 + c] = acc[nf][r];
  }
  __syncthreads();
  if (tid < 64) {
    int t = t0 + tid;
    float* lg = &llog[tid*NPAD];
    float m = -1e30f;
    for (int e = 0; e < ETOT; e++) {
      float v = lg[e];
      logits_out[(size_t)t*ETOT + e] = v;
      m = fmaxf(m, v);
    }
    float s = 0.f;
    for (int e = 0; e < ETOT; e++) s += __expf(lg[e] - m);
    uint64_t m0 = 0; unsigned int m1 = 0;
    for (int k = 0; k < TOPK; k++) {
      float best = -1e30f; int bi = 0;
      for (int e = 0; e < ETOT; e++) {
        bool used = (e < 64) ? ((m0 >> e) & 1) : ((m1 >> (e-64)) & 1);
        float v = lg[e];
        if (!used && v > best) { best = v; bi = e; }
      }
      if (bi < 64) m0 |= (1ull << bi); else m1 |= (1u << (bi-64));
      tk_idx[t*TOPK + k] = bi;
      tk_w[t*TOPK + k] = __expf(best - m) / s;
      if (bi < NEXP) atomicAdd(&counts[bi], 1);
    }
  }
}

// ---------------- K2: scan ----------------
__global__ void k_scan(const int* __restrict__ counts, int* __restrict__ offsets,
                       int* __restrict__ cursors) {
  if (threadIdx.x == 0) {
    int s = 0;
    for (int e = 0; e < NEXP; e++) { offsets[e] = s; cursors[e] = s; s += counts[e]; }
  }
}

// ---------------- K3: build grouped lists ----------------
__global__ void k_build(const int* __restrict__ tk_idx, const float* __restrict__ tk_w,
                        int* __restrict__ cursors, int* __restrict__ rows,
                        float* __restrict__ rwgt) {
  int t = blockIdx.x * blockDim.x + threadIdx.x;
  if (t >= T_TOK) return;
#pragma unroll
  for (int k = 0; k < TOPK; k++) {
    int e = tk_idx[t*TOPK + k];
    if (e < NEXP) {
      int p = atomicAdd(&cursors[e], 1);
      rows[p] = t;
      rwgt[p] = tk_w[t*TOPK + k];
    }
  }
}

// ---------------- K4: grouped gate/up GEMM (bf16 [n][k] weights) --------------
// Tile 128m x 256n, 512 thr / 8 waves (2m x 4n, wave 64x64). Lockstep single
// buffer (stage -> sync -> compute -> sync) -- round 7 proved prefetch breaks
// sibling L2 dedup. N=256 halves gathered-A L2 re-reads (8 -> 4), the round-6
// limiter. launch_bounds(512,4) = 2 blocks/CU, VGPR cap high (no r8 spill).
__launch_bounds__(512, 4)
__global__ void k_expert_gu(const u16* __restrict__ xh, const u16* __restrict__ wgT,
                            const u16* __restrict__ wuT, const int* __restrict__ counts,
                            const int* __restrict__ offsets, const int* __restrict__ rows,
                            u16* __restrict__ inter) {
  int wgid = blockIdx.x;
  int xcd = wgid & 7, slot = wgid >> 3;   // 256 slots per XCD
  int m = slot & 7, q = slot >> 3;        // q = 0..31
  int g = xcd * 32 + q;                   // group 0..255
  int e = g >> 2, nb = g & 3;             // FFN/256 = 4 n-blocks
  int cnt = counts[e];
  if (cnt == 0) return;
  int off = offsets[e];
  int n0 = nb * 256;
  int tid = threadIdx.x, lane = tid & 63, wid = tid >> 6;   // wid 0..7
  int wm = (wid >> 2) * 64, wn = (wid & 3) * 64;
  __shared__ __align__(16) char smem[40960];
  u16* la  = (u16*)smem;                // [128*32]  8 KB
  u16* lbg = (u16*)(smem + 8192);       // [256*32] 16 KB
  u16* lbu = (u16*)(smem + 24576);      // [256*32] 16 KB
  u16* lout = (u16*)smem;               // epilogue overlay [64][256] 32 KB
  int rsub = lane >> 2, csub = lane & 3;
  int swzc = csub ^ ((rsub >> 1) & 3);
  int arow = wid * 16 + rsub;           // A row 0..127
  int bn1 = wid * 32 + rsub, bn2 = bn1 + 16;   // B rows 0..255
  const u16* gb_g1 = wgT + ((size_t)e*FFN + n0 + bn1)*HID + swzc*8;
  const u16* gb_g2 = wgT + ((size_t)e*FFN + n0 + bn2)*HID + swzc*8;
  const u16* gb_u1 = wuT + ((size_t)e*FFN + n0 + bn1)*HID + swzc*8;
  const u16* gb_u2 = wuT + ((size_t)e*FFN + n0 + bn2)*HID + swzc*8;

  for (int m0 = m * 128; m0 < cnt; m0 += 1024) {
    int tok = (m0 + arow < cnt) ? rows[off + m0 + arow] : 0;
    const u16* ga = xh + (size_t)tok*HID + swzc*8;
    f32x4 accg[4][4] = {}, accu[4][4] = {};
#pragma unroll 1
    for (int k0 = 0; k0 < HID; k0 += 32) {
      gload16(ga + k0, &la[wid*512]);
      gload16(gb_g1 + k0, &lbg[wid*1024]);
      gload16(gb_g2 + k0, &lbg[wid*1024 + 512]);
      gload16(gb_u1 + k0, &lbu[wid*1024]);
      gload16(gb_u2 + k0, &lbu[wid*1024 + 512]);
      __syncthreads();
      bf16x8 afr[4], bgf[4], buf_[4];
#pragma unroll
      for (int i = 0; i < 4; i++) {
        int row = wm + i*16 + (lane & 15);
        int ch = (lane >> 4) ^ ((row >> 1) & 3);
        afr[i] = *(const bf16x8*)&la[row*32 + ch*8];
        int n = wn + i*16 + (lane & 15);
        int chb = (lane >> 4) ^ ((n >> 1) & 3);
        bgf[i]  = *(const bf16x8*)&lbg[n*32 + chb*8];
        buf_[i] = *(const bf16x8*)&lbu[n*32 + chb*8];
      }
#pragma unroll
      for (int nf = 0; nf < 4; nf++)
#pragma unroll
        for (int mf = 0; mf < 4; mf++) {
          accg[mf][nf] = mfma16(afr[mf], bgf[nf], accg[mf][nf]);
          accu[mf][nf] = mfma16(afr[mf], buf_[nf], accu[mf][nf]);
        }
      __syncthreads();
    }
    // epilogue: silu(g)*u, two 64-row passes through lout overlay
#pragma unroll
    for (int pass = 0; pass < 2; pass++) {
      if ((wid >> 2) == pass) {
#pragma unroll
        for (int mf = 0; mf < 4; mf++)
#pragma unroll
          for (int nf = 0; nf < 4; nf++)
#pragma unroll
            for (int r = 0; r < 4; r++) {
              float gg = accg[mf][nf][r], uu = accu[mf][nf][r];
              float v = gg / (1.f + __expf(-gg)) * uu;
              int row = mf*16 + (lane >> 4)*4 + r;      // 0..63 local
              int col = wn + nf*16 + (lane & 15);       // 0..255
              U2 t; t.h[0] = (bf16)v; t.h[1] = (bf16)0.f;
              lout[row*256 + col] = (u16)(t.u & 0xffffu);
            }
      }
      __syncthreads();
      for (int idx = tid; idx < 2048; idx += 512) {
        int row = idx >> 5, c8 = idx & 31;
        int grow = m0 + pass*64 + row;
        if (grow < cnt) {
          uint4 v = *(const uint4*)&lout[row*256 + c8*8];
          *(uint4*)&inter[(size_t)(off + grow)*FFN + n0 + c8*8] = v;
        }
      }
      __syncthreads();
    }
  }
}

// ---------------- K5: grouped down GEMM (bf16 wdT), atomic scatter-add --------
// Tile 128m x 256n, 512 thr / 8 waves, lockstep single buffer, LDS 24 KB.
__launch_bounds__(512, 4)
__global__ void k_expert_down(const u16* __restrict__ inter, const u16* __restrict__ wdT,
                              const int* __restrict__ counts, const int* __restrict__ offsets,
                              const int* __restrict__ rows, const float* __restrict__ rwgt,
                              float* __restrict__ out) {
  int wgid = blockIdx.x;
  int xcd = wgid & 7, slot = wgid >> 3;   // 256 slots per XCD
  int m = slot & 3, q = slot >> 2;        // q = 0..63
  int g = xcd * 64 + q;                   // group 0..511
  int e = g >> 3, nb = g & 7;             // HID/256 = 8 n-blocks
  int cnt = counts[e];
  if (cnt == 0) return;
  int off = offsets[e];
  int n0 = nb * 256;
  int tid = threadIdx.x, lane = tid & 63, wid = tid >> 6;
  int wm = (wid >> 2) * 64, wn = (wid & 3) * 64;
  __shared__ __align__(16) char smem[24576];
  u16* la = (u16*)smem;                  // [128*32]  8 KB
  u16* lb = (u16*)(smem + 8192);         // [256*32] 16 KB
  __shared__ int rows_l[128];
  __shared__ float rw_l[128];
  int rsub = lane >> 2, csub = lane & 3;
  int swzc = csub ^ ((rsub >> 1) & 3);
  int arow = wid * 16 + rsub;
  int bn1 = wid * 32 + rsub, bn2 = bn1 + 16;
  const u16* gb1 = wdT + ((size_t)e*HID + n0 + bn1)*FFN + swzc*8;
  const u16* gb2 = wdT + ((size_t)e*HID + n0 + bn2)*FFN + swzc*8;

  for (int m0 = m * 128; m0 < cnt; m0 += 512) {
    __syncthreads();
    if (tid < 128) {
      int r = m0 + tid;
      rows_l[tid] = (r < cnt) ? rows[off + r] : 0;
      rw_l[tid]   = (r < cnt) ? rwgt[off + r] : 0.f;
    }
    const u16* ga = inter + (size_t)(off + m0 + arow)*FFN + swzc*8;  // inter has slack
    f32x4 acc[4][4] = {};
#pragma unroll 1
    for (int k0 = 0; k0 < FFN; k0 += 32) {
      gload16(ga + k0, &la[wid*512]);
      gload16(gb1 + k0, &lb[wid*1024]);
      gload16(gb2 + k0, &lb[wid*1024 + 512]);
      __syncthreads();
      bf16x8 afr[4], bfr[4];
#pragma unroll
      for (int i = 0; i < 4; i++) {
        int row = wm + i*16 + (lane & 15);
        int ch = (lane >> 4) ^ ((row >> 1) & 3);
        afr[i] = *(const bf16x8*)&la[row*32 + ch*8];
        int n = wn + i*16 + (lane & 15);
        int chb = (lane >> 4) ^ ((n >> 1) & 3);
        bfr[i] = *(const bf16x8*)&lb[n*32 + chb*8];
      }
#pragma unroll
      for (int nf = 0; nf < 4; nf++)
#pragma unroll
        for (int mf = 0; mf < 4; mf++)
          acc[mf][nf] = mfma16(afr[mf], bfr[nf], acc[mf][nf]);
      __syncthreads();
    }
#pragma unroll
    for (int mf = 0; mf < 4; mf++)
#pragma unroll
      for (int nf = 0; nf < 4; nf++)
#pragma unroll
        for (int r = 0; r < 4; r++) {
          int row = wm + mf*16 + (lane >> 4)*4 + r;
          if (m0 + row < cnt) {
            int tok = rows_l[row];
            float w = rw_l[row];
            int col = n0 + wn + nf*16 + (lane & 15);
            atomicAdd(&out[(size_t)tok*HID + col], w * acc[mf][nf][r]);
          }
        }
  }
}

// ---------------- launch ----------------
extern "C" void kernel_launch(void* const* d_in, const int* in_sizes, int n_in,
                              void* d_out, int out_size, void* d_ws, size_t ws_size,
                              hipStream_t stream) {
  const float* x      = (const float*)d_in[0];
  const float* gate_w = (const float*)d_in[1];
  const float* wg     = (const float*)d_in[2];
  const float* wu     = (const float*)d_in[3];
  const float* wd     = (const float*)d_in[4];
  float* out = (float*)d_out;
  float* logits_out = out + (size_t)T_TOK * HID;

  char* w = (char*)d_ws;
  u16* xh = (u16*)w;            w += (size_t)T_TOK*HID*2;
  u16* xl = (u16*)w;            w += (size_t)T_TOK*HID*2;
  u16* gh = (u16*)w;            w += (size_t)NPAD*HID*2;
  u16* gl = (u16*)w;            w += (size_t)NPAD*HID*2;
  int* tk_idx = (int*)w;        w += (size_t)T_TOK*TOPK*4;
  float* tk_w = (float*)w;      w += (size_t)T_TOK*TOPK*4;
  int* counts = (int*)w;        w += 256;
  int* offsets = (int*)w;       w += 256;
  int* cursors = (int*)w;       w += 256;
  int* rows = (int*)w;          w += (size_t)NASSIGN*4;
  float* rwgt = (float*)w;      w += (size_t)NASSIGN*4;
  u16* inter = (u16*)w;         w += ((size_t)NASSIGN + 256)*FFN*2;
  u16* wgT = (u16*)w;           w += (size_t)NEXP*FFN*HID*2;
  u16* wuT = (u16*)w;           w += (size_t)NEXP*FFN*HID*2;
  u16* wdT = (u16*)w;           // NEXP*HID*FFN*2

  hipMemsetAsync(d_out, 0, (size_t)T_TOK*HID*4, stream);
  hipMemsetAsync(counts, 0, 256, stream);

  k_prep_x<<<2048, 256, 0, stream>>>(x, xh, xl, T_TOK*HID/8);
  k_prep_gate<<<NPAD, 256, 0, stream>>>(gate_w, gh, gl);
  k_router<<<T_TOK/64, 256, 0, stream>>>(xh, xl, gh, gl, logits_out, tk_idx, tk_w, counts);
  k_scan<<<1, 64, 0, stream>>>(counts, offsets, cursors);
  k_build<<<T_TOK/256, 256, 0, stream>>>(tk_idx, tk_w, cursors, rows, rwgt);

  // one-shot full weight conversion to bf16 [n][k]
  k_convT<<<dim3(FFN/64, HID/128, NEXP), 256, 0, stream>>>(wg, wgT, HID, FFN);
  k_convT<<<dim3(FFN/64, HID/128, NEXP), 256, 0, stream>>>(wu, wuT, HID, FFN);
  k_convT<<<dim3(HID/64, FFN/128, NEXP), 256, 0, stream>>>(wd, wdT, FFN, HID);

  k_expert_gu<<<2048, 512, 0, stream>>>(xh, wgT, wuT, counts, offsets, rows, inter);
  k_expert_down<<<2048, 512, 0, stream>>>(inter, wdT, counts, offsets, rows, rwgt, out);
}

// Round 10
// 1959.495 us; speedup vs baseline: 4.2486x; 2.4734x over previous
//
#include <hip/hip_runtime.h>
#include <hip/hip_bf16.h>
#include <stdint.h>

#define T_TOK 8192
#define HID   2048
#define FFN   1024
#define NEXP  64
#define ETOT  72
#define NPAD  80
#define TOPK  8
#define NASSIGN (T_TOK*TOPK)

typedef unsigned short u16;
typedef __bf16 bf16;
typedef bf16 bf16x8 __attribute__((ext_vector_type(8)));
typedef float f32x4 __attribute__((ext_vector_type(4)));

typedef const __attribute__((address_space(1))) void* gp_t;
typedef __attribute__((address_space(3))) void* lp_t;

__device__ __forceinline__ void gload16(const void* g, void* lds) {
  __builtin_amdgcn_global_load_lds((gp_t)g, (lp_t)lds, 16, 0, 0);
}
__device__ __forceinline__ f32x4 mfma16(bf16x8 a, bf16x8 b, f32x4 c) {
  return __builtin_amdgcn_mfma_f32_16x16x32_bf16(a, b, c, 0, 0, 0);
}

union U8 { bf16 h[8]; uint4 u; };
union U2 { bf16 h[2]; unsigned int u; };

// ---------------- K0: fp32 -> bf16 hi/lo split of x ----------------
__global__ void k_prep_x(const float* __restrict__ x, u16* __restrict__ xh,
                         u16* __restrict__ xl, int n8) {
  int i = blockIdx.x * blockDim.x + threadIdx.x;
  int stride = gridDim.x * blockDim.x;
  for (; i < n8; i += stride) {
    const float4* p = (const float4*)(x + (size_t)i * 8);
    float4 a = p[0], b = p[1];
    float f[8] = {a.x,a.y,a.z,a.w,b.x,b.y,b.z,b.w};
    U8 hh, ll;
#pragma unroll
    for (int j = 0; j < 8; j++) {
      bf16 h = (bf16)f[j];
      hh.h[j] = h;
      ll.h[j] = (bf16)(f[j] - (float)h);
    }
    ((uint4*)xh)[i] = hh.u;
    ((uint4*)xl)[i] = ll.u;
  }
}

// ---------------- K0b: gate_w -> bf16 hi/lo, padded to 80 rows ----------------
__global__ void k_prep_gate(const float* __restrict__ gw, u16* __restrict__ gh,
                            u16* __restrict__ gl) {
  int e = blockIdx.x;
  for (int k8 = threadIdx.x; k8 < HID/8; k8 += blockDim.x) {
    U8 hh, ll;
    if (e < ETOT) {
      const float4* p = (const float4*)(gw + (size_t)e*HID + k8*8);
      float4 a = p[0], b = p[1];
      float f[8] = {a.x,a.y,a.z,a.w,b.x,b.y,b.z,b.w};
#pragma unroll
      for (int j = 0; j < 8; j++) {
        bf16 h = (bf16)f[j]; hh.h[j] = h; ll.h[j] = (bf16)(f[j]-(float)h);
      }
    } else {
      hh.u = make_uint4(0,0,0,0); ll.u = make_uint4(0,0,0,0);
    }
    ((uint4*)gh)[(size_t)e*(HID/8) + k8] = hh.u;
    ((uint4*)gl)[(size_t)e*(HID/8) + k8] = ll.u;
  }
}

// ---------------- K0c: fp32 [R][C] -> bf16 [C][R] transpose-convert ----------------
__global__ void k_convT(const float* __restrict__ src, u16* __restrict__ dst,
                        int R, int C) {
  int e = blockIdx.z;
  src += (size_t)e * R * C;
  dst += (size_t)e * R * C;
  int c0 = blockIdx.x * 64, r0 = blockIdx.y * 128;
  __shared__ u16 t[64 * 132];
  int tid = threadIdx.x;
  int rr = tid >> 4, cc = (tid & 15) * 4;
#pragma unroll
  for (int it = 0; it < 8; it++) {
    int r = it * 16 + rr;
    float4 v = *(const float4*)(src + (size_t)(r0 + r) * C + c0 + cc);
    const float* f = &v.x;
#pragma unroll
    for (int i = 0; i < 4; i++) {
      U2 u; u.h[0] = (bf16)f[i]; u.h[1] = (bf16)0.f;
      t[(cc + i) * 132 + r] = (u16)(u.u & 0xffffu);
    }
  }
  __syncthreads();
  int n = tid >> 2, kb = (tid & 3) * 32;
  u16* drow = dst + (size_t)(c0 + n) * R + r0 + kb;
  const u16* srow = &t[n * 132 + kb];
#pragma unroll
  for (int j = 0; j < 2; j++) {
    uint2 a = *(const uint2*)&srow[j*16 + 0];
    uint2 b = *(const uint2*)&srow[j*16 + 4];
    uint2 c = *(const uint2*)&srow[j*16 + 8];
    uint2 d = *(const uint2*)&srow[j*16 + 12];
    *(uint4*)&drow[j*16]     = make_uint4(a.x, a.y, b.x, b.y);
    *(uint4*)&drow[j*16 + 8] = make_uint4(c.x, c.y, d.x, d.y);
  }
}

// ---------------- K1: router ----------------
__global__ void k_router(const u16* __restrict__ xh, const u16* __restrict__ xl,
                         const u16* __restrict__ gh, const u16* __restrict__ gl,
                         float* __restrict__ logits_out, int* __restrict__ tk_idx,
                         float* __restrict__ tk_w, int* __restrict__ counts) {
  __shared__ u16 la_h[64*32], la_l[64*32], lb_h[NPAD*32], lb_l[NPAD*32];
  __shared__ float llog[64*NPAD];
  int tid = threadIdx.x, lane = tid & 63, wid = tid >> 6;
  int t0 = blockIdx.x * 64;
  int rsub = lane >> 2, csub = lane & 3;
  f32x4 acc[5] = {};
#pragma unroll 1
  for (int k0 = 0; k0 < HID; k0 += 32) {
    int arow = wid*16 + rsub;
    gload16(xh + (size_t)(t0+arow)*HID + k0 + csub*8, &la_h[wid*512]);
    gload16(xl + (size_t)(t0+arow)*HID + k0 + csub*8, &la_l[wid*512]);
    int brow = wid*16 + rsub;
    gload16(gh + (size_t)brow*HID + k0 + csub*8, &lb_h[wid*512]);
    gload16(gl + (size_t)brow*HID + k0 + csub*8, &lb_l[wid*512]);
    if (wid == 0) gload16(gh + (size_t)(64+rsub)*HID + k0 + csub*8, &lb_h[4*512]);
    if (wid == 1) gload16(gl + (size_t)(64+rsub)*HID + k0 + csub*8, &lb_l[4*512]);
    __syncthreads();
    int ar = wid*16 + (lane & 15);
    int ks = lane >> 4;
    bf16x8 ah = *(const bf16x8*)&la_h[ar*32 + ks*8];
    bf16x8 al = *(const bf16x8*)&la_l[ar*32 + ks*8];
#pragma unroll
    for (int nf = 0; nf < 5; nf++) {
      int br = nf*16 + (lane & 15);
      bf16x8 bh = *(const bf16x8*)&lb_h[br*32 + ks*8];
      bf16x8 bl = *(const bf16x8*)&lb_l[br*32 + ks*8];
      acc[nf] = mfma16(ah, bh, acc[nf]);
      acc[nf] = mfma16(ah, bl, acc[nf]);
      acc[nf] = mfma16(al, bh, acc[nf]);
    }
    __syncthreads();
  }
  {
    int q = lane >> 4, c = lane & 15;
#pragma unroll
    for (int nf = 0; nf < 5; nf++)
#pragma unroll
      for (int r = 0; r < 4; r++)
        llog[(wid*16 + q*4 + r)*NPAD + nf*16 + c] = acc[nf][r];
  }
  __syncthreads();
  if (tid < 64) {
    int t = t0 + tid;
    float* lg = &llog[tid*NPAD];
    float m = -1e30f;
    for (int e = 0; e < ETOT; e++) {
      float v = lg[e];
      logits_out[(size_t)t*ETOT + e] = v;
      m = fmaxf(m, v);
    }
    float s = 0.f;
    for (int e = 0; e < ETOT; e++) s += __expf(lg[e] - m);
    uint64_t m0 = 0; unsigned int m1 = 0;
    for (int k = 0; k < TOPK; k++) {
      float best = -1e30f; int bi = 0;
      for (int e = 0; e < ETOT; e++) {
        bool used = (e < 64) ? ((m0 >> e) & 1) : ((m1 >> (e-64)) & 1);
        float v = lg[e];
        if (!used && v > best) { best = v; bi = e; }
      }
      if (bi < 64) m0 |= (1ull << bi); else m1 |= (1u << (bi-64));
      tk_idx[t*TOPK + k] = bi;
      tk_w[t*TOPK + k] = __expf(best - m) / s;
      if (bi < NEXP) atomicAdd(&counts[bi], 1);
    }
  }
}

// ---------------- K2: scan ----------------
__global__ void k_scan(const int* __restrict__ counts, int* __restrict__ offsets,
                       int* __restrict__ cursors) {
  if (threadIdx.x == 0) {
    int s = 0;
    for (int e = 0; e < NEXP; e++) { offsets[e] = s; cursors[e] = s; s += counts[e]; }
  }
}

// ---------------- K3: build grouped lists ----------------
__global__ void k_build(const int* __restrict__ tk_idx, const float* __restrict__ tk_w,
                        int* __restrict__ cursors, int* __restrict__ rows,
                        float* __restrict__ rwgt) {
  int t = blockIdx.x * blockDim.x + threadIdx.x;
  if (t >= T_TOK) return;
#pragma unroll
  for (int k = 0; k < TOPK; k++) {
    int e = tk_idx[t*TOPK + k];
    if (e < NEXP) {
      int p = atomicAdd(&cursors[e], 1);
      rows[p] = t;
      rwgt[p] = tk_w[t*TOPK + k];
    }
  }
}

// ---------------- K4a: grouped GATE GEMM -> G (bf16) into inter --------------
// 128x128 tile, 4 waves 2x2, single acc (64 regs) -> (256,4) real occupancy.
// Lockstep single-buffer loop (r6-verified traffic-optimal). XCD-grouped decode.
__launch_bounds__(256, 4)
__global__ void k_gate(const u16* __restrict__ xh, const u16* __restrict__ wT,
                       const int* __restrict__ counts, const int* __restrict__ offsets,
                       const int* __restrict__ rows, u16* __restrict__ gout) {
  int wgid = blockIdx.x;
  int xcd = wgid & 7, slot = wgid >> 3;
  int m = slot & 7, q = slot >> 3;
  int g = xcd * 64 + q;
  int e = g >> 3, nb = g & 7;
  int cnt = counts[e];
  if (cnt == 0) return;
  int off = offsets[e];
  int n0 = nb * 128;
  int tid = threadIdx.x, lane = tid & 63, wid = tid >> 6;
  int wm = (wid >> 1) * 64, wn = (wid & 1) * 64;
  __shared__ __align__(16) char smem[16384];
  u16* la = (u16*)smem;                  // [128*32] 8 KB
  u16* lb = (u16*)(smem + 8192);         // [128*32] 8 KB
  u16* lout = (u16*)smem;                // epilogue overlay [64][128] 16 KB
  int rsub = lane >> 2, csub = lane & 3;
  int swzc = csub ^ ((rsub >> 1) & 3);
  int nr1 = wid*16 + rsub, nr2 = nr1 + 64;
  const u16* gb1 = wT + ((size_t)e*FFN + n0 + nr1)*HID + swzc*8;
  const u16* gb2 = wT + ((size_t)e*FFN + n0 + nr2)*HID + swzc*8;

  for (int m0 = m * 128; m0 < cnt; m0 += 1024) {
    int tok1 = (m0 + nr1 < cnt) ? rows[off + m0 + nr1] : 0;
    int tok2 = (m0 + nr2 < cnt) ? rows[off + m0 + nr2] : 0;
    const u16* ga1 = xh + (size_t)tok1*HID + swzc*8;
    const u16* ga2 = xh + (size_t)tok2*HID + swzc*8;
    f32x4 acc[4][4] = {};
#pragma unroll 1
    for (int k0 = 0; k0 < HID; k0 += 32) {
      gload16(ga1 + k0, &la[wid*512]);
      gload16(ga2 + k0, &la[(wid+4)*512]);
      gload16(gb1 + k0, &lb[wid*512]);
      gload16(gb2 + k0, &lb[(wid+4)*512]);
      __syncthreads();
      bf16x8 afr[4], bfr[4];
#pragma unroll
      for (int i = 0; i < 4; i++) {
        int row = wm + i*16 + (lane & 15);
        int ch = (lane >> 4) ^ ((row >> 1) & 3);
        afr[i] = *(const bf16x8*)&la[row*32 + ch*8];
        int n = wn + i*16 + (lane & 15);
        int chb = (lane >> 4) ^ ((n >> 1) & 3);
        bfr[i] = *(const bf16x8*)&lb[n*32 + chb*8];
      }
#pragma unroll
      for (int nf = 0; nf < 4; nf++)
#pragma unroll
        for (int mf = 0; mf < 4; mf++)
          acc[mf][nf] = mfma16(afr[mf], bfr[nf], acc[mf][nf]);
      __syncthreads();
    }
    // epilogue: write G bf16, two 64-row passes through lout overlay
#pragma unroll
    for (int pass = 0; pass < 2; pass++) {
      if ((wid >> 1) == pass) {
#pragma unroll
        for (int mf = 0; mf < 4; mf++)
#pragma unroll
          for (int nf = 0; nf < 4; nf++)
#pragma unroll
            for (int r = 0; r < 4; r++) {
              int row = mf*16 + (lane >> 4)*4 + r;
              int col = wn + nf*16 + (lane & 15);
              U2 t; t.h[0] = (bf16)acc[mf][nf][r]; t.h[1] = (bf16)0.f;
              lout[row*128 + col] = (u16)(t.u & 0xffffu);
            }
      }
      __syncthreads();
      for (int idx = tid; idx < 1024; idx += 256) {
        int row = idx >> 4, c16 = idx & 15;
        int grow = m0 + pass*64 + row;
        if (grow < cnt) {
          uint4 v = *(const uint4*)&lout[row*128 + c16*8];
          *(uint4*)&gout[(size_t)(off + grow)*FFN + n0 + c16*8] = v;
        }
      }
      __syncthreads();
    }
  }
}

// ---------------- K4b: grouped UP GEMM + silu(G)*U -> inter (in place) --------
// Same loop; epilogue loads the G-half from inter via LDS, combines, overwrites.
__launch_bounds__(256, 4)
__global__ void k_up(const u16* __restrict__ xh, const u16* __restrict__ wT,
                     const int* __restrict__ counts, const int* __restrict__ offsets,
                     const int* __restrict__ rows, u16* __restrict__ inter) {
  int wgid = blockIdx.x;
  int xcd = wgid & 7, slot = wgid >> 3;
  int m = slot & 7, q = slot >> 3;
  int g = xcd * 64 + q;
  int e = g >> 3, nb = g & 7;
  int cnt = counts[e];
  if (cnt == 0) return;
  int off = offsets[e];
  int n0 = nb * 128;
  int tid = threadIdx.x, lane = tid & 63, wid = tid >> 6;
  int wm = (wid >> 1) * 64, wn = (wid & 1) * 64;
  __shared__ __align__(16) char smem[32768];
  u16* la = (u16*)smem;                  // [128*32] 8 KB
  u16* lb = (u16*)(smem + 8192);         // [128*32] 8 KB
  u16* lg = (u16*)smem;                  // epilogue overlay: G half [64][128] 16 KB
  u16* lout = (u16*)(smem + 16384);      // epilogue out [64][128] 16 KB
  int rsub = lane >> 2, csub = lane & 3;
  int swzc = csub ^ ((rsub >> 1) & 3);
  int nr1 = wid*16 + rsub, nr2 = nr1 + 64;
  const u16* gb1 = wT + ((size_t)e*FFN + n0 + nr1)*HID + swzc*8;
  const u16* gb2 = wT + ((size_t)e*FFN + n0 + nr2)*HID + swzc*8;

  for (int m0 = m * 128; m0 < cnt; m0 += 1024) {
    int tok1 = (m0 + nr1 < cnt) ? rows[off + m0 + nr1] : 0;
    int tok2 = (m0 + nr2 < cnt) ? rows[off + m0 + nr2] : 0;
    const u16* ga1 = xh + (size_t)tok1*HID + swzc*8;
    const u16* ga2 = xh + (size_t)tok2*HID + swzc*8;
    f32x4 acc[4][4] = {};
#pragma unroll 1
    for (int k0 = 0; k0 < HID; k0 += 32) {
      gload16(ga1 + k0, &la[wid*512]);
      gload16(ga2 + k0, &la[(wid+4)*512]);
      gload16(gb1 + k0, &lb[wid*512]);
      gload16(gb2 + k0, &lb[(wid+4)*512]);
      __syncthreads();
      bf16x8 afr[4], bfr[4];
#pragma unroll
      for (int i = 0; i < 4; i++) {
        int row = wm + i*16 + (lane & 15);
        int ch = (lane >> 4) ^ ((row >> 1) & 3);
        afr[i] = *(const bf16x8*)&la[row*32 + ch*8];
        int n = wn + i*16 + (lane & 15);
        int chb = (lane >> 4) ^ ((n >> 1) & 3);
        bfr[i] = *(const bf16x8*)&lb[n*32 + chb*8];
      }
#pragma unroll
      for (int nf = 0; nf < 4; nf++)
#pragma unroll
        for (int mf = 0; mf < 4; mf++)
          acc[mf][nf] = mfma16(afr[mf], bfr[nf], acc[mf][nf]);
      __syncthreads();
    }
    // epilogue: per 64-row half: load G from inter -> lg, silu(G)*U -> lout, store
#pragma unroll
    for (int pass = 0; pass < 2; pass++) {
      for (int idx = tid; idx < 1024; idx += 256) {
        int row = idx >> 4, c16 = idx & 15;
        int grow = m0 + pass*64 + row;
        uint4 v = make_uint4(0,0,0,0);
        if (grow < cnt)
          v = *(const uint4*)&inter[(size_t)(off + grow)*FFN + n0 + c16*8];
        *(uint4*)&lg[row*128 + c16*8] = v;
      }
      __syncthreads();
      if ((wid >> 1) == pass) {
#pragma unroll
        for (int mf = 0; mf < 4; mf++)
#pragma unroll
          for (int nf = 0; nf < 4; nf++)
#pragma unroll
            for (int r = 0; r < 4; r++) {
              int row = mf*16 + (lane >> 4)*4 + r;
              int col = wn + nf*16 + (lane & 15);
              U2 gv; gv.u = (unsigned int)lg[row*128 + col];
              float gg = (float)gv.h[0];
              float v = gg / (1.f + __expf(-gg)) * acc[mf][nf][r];
              U2 t; t.h[0] = (bf16)v; t.h[1] = (bf16)0.f;
              lout[row*128 + col] = (u16)(t.u & 0xffffu);
            }
      }
      __syncthreads();
      for (int idx = tid; idx < 1024; idx += 256) {
        int row = idx >> 4, c16 = idx & 15;
        int grow = m0 + pass*64 + row;
        if (grow < cnt) {
          uint4 v = *(const uint4*)&lout[row*128 + c16*8];
          *(uint4*)&inter[(size_t)(off + grow)*FFN + n0 + c16*8] = v;
        }
      }
      __syncthreads();
    }
  }
}

// ---------------- K5: grouped down GEMM (bf16 wdT), atomic scatter-add --------
// r6 verbatim: 128x128 tile, single-buffer lockstep, (256,4).
__launch_bounds__(256, 4)
__global__ void k_expert_down(const u16* __restrict__ inter, const u16* __restrict__ wdT,
                              const int* __restrict__ counts, const int* __restrict__ offsets,
                              const int* __restrict__ rows, const float* __restrict__ rwgt,
                              float* __restrict__ out) {
  int wgid = blockIdx.x;
  int xcd = wgid & 7, slot = wgid >> 3;
  int m = slot & 3, q = slot >> 2;
  int g = xcd * 128 + q;
  int e = g >> 4, nb = g & 15;
  int cnt = counts[e];
  if (cnt == 0) return;
  int off = offsets[e];
  int n0 = nb * 128;
  int tid = threadIdx.x, lane = tid & 63, wid = tid >> 6;
  int wm = (wid >> 1) * 64, wn = (wid & 1) * 64;
  __shared__ u16 la[128*32], lb[128*32];
  __shared__ int rows_l[128];
  __shared__ float rw_l[128];
  int rsub = lane >> 2, csub = lane & 3;
  int swzc = csub ^ ((rsub >> 1) & 3);
  int nr1 = wid*16 + rsub, nr2 = nr1 + 64;
  const u16* gb1 = wdT + ((size_t)e*HID + n0 + nr1)*FFN + swzc*8;
  const u16* gb2 = wdT + ((size_t)e*HID + n0 + nr2)*FFN + swzc*8;

  for (int m0 = m * 128; m0 < cnt; m0 += 512) {
    __syncthreads();
    if (tid < 128) {
      int r = m0 + tid;
      rows_l[tid] = (r < cnt) ? rows[off + r] : 0;
      rw_l[tid]   = (r < cnt) ? rwgt[off + r] : 0.f;
    }
    const u16* ga1 = inter + (size_t)(off + m0 + nr1)*FFN + swzc*8;
    const u16* ga2 = inter + (size_t)(off + m0 + nr2)*FFN + swzc*8;
    f32x4 acc[4][4] = {};
#pragma unroll 1
    for (int k0 = 0; k0 < FFN; k0 += 32) {
      gload16(ga1 + k0, &la[wid*512]);
      gload16(ga2 + k0, &la[(wid+4)*512]);
      gload16(gb1 + k0, &lb[wid*512]);
      gload16(gb2 + k0, &lb[(wid+4)*512]);
      __syncthreads();
      bf16x8 afr[4], bfr[4];
#pragma unroll
      for (int i = 0; i < 4; i++) {
        int row = wm + i*16 + (lane & 15);
        int ch = (lane >> 4) ^ ((row >> 1) & 3);
        afr[i] = *(const bf16x8*)&la[row*32 + ch*8];
        int n = wn + i*16 + (lane & 15);
        int chb = (lane >> 4) ^ ((n >> 1) & 3);
        bfr[i] = *(const bf16x8*)&lb[n*32 + chb*8];
      }
#pragma unroll
      for (int nf = 0; nf < 4; nf++)
#pragma unroll
        for (int mf = 0; mf < 4; mf++)
          acc[mf][nf] = mfma16(afr[mf], bfr[nf], acc[mf][nf]);
      __syncthreads();
    }
#pragma unroll
    for (int mf = 0; mf < 4; mf++)
#pragma unroll
      for (int nf = 0; nf < 4; nf++)
#pragma unroll
        for (int r = 0; r < 4; r++) {
          int row = wm + mf*16 + (lane >> 4)*4 + r;
          if (m0 + row < cnt) {
            int tok = rows_l[row];
            float w = rw_l[row];
            int col = n0 + wn + nf*16 + (lane & 15);
            atomicAdd(&out[(size_t)tok*HID + col], w * acc[mf][nf][r]);
          }
        }
  }
}

// ---------------- launch ----------------
extern "C" void kernel_launch(void* const* d_in, const int* in_sizes, int n_in,
                              void* d_out, int out_size, void* d_ws, size_t ws_size,
                              hipStream_t stream) {
  const float* x      = (const float*)d_in[0];
  const float* gate_w = (const float*)d_in[1];
  const float* wg     = (const float*)d_in[2];
  const float* wu     = (const float*)d_in[3];
  const float* wd     = (const float*)d_in[4];
  float* out = (float*)d_out;
  float* logits_out = out + (size_t)T_TOK * HID;

  char* w = (char*)d_ws;
  u16* xh = (u16*)w;            w += (size_t)T_TOK*HID*2;
  u16* xl = (u16*)w;            w += (size_t)T_TOK*HID*2;
  u16* gh = (u16*)w;            w += (size_t)NPAD*HID*2;
  u16* gl = (u16*)w;            w += (size_t)NPAD*HID*2;
  int* tk_idx = (int*)w;        w += (size_t)T_TOK*TOPK*4;
  float* tk_w = (float*)w;      w += (size_t)T_TOK*TOPK*4;
  int* counts = (int*)w;        w += 256;
  int* offsets = (int*)w;       w += 256;
  int* cursors = (int*)w;       w += 256;
  int* rows = (int*)w;          w += (size_t)NASSIGN*4;
  float* rwgt = (float*)w;      w += (size_t)NASSIGN*4;
  u16* inter = (u16*)w;         w += ((size_t)NASSIGN + 256)*FFN*2;
  u16* wgT = (u16*)w;           w += (size_t)NEXP*FFN*HID*2;
  u16* wuT = (u16*)w;           w += (size_t)NEXP*FFN*HID*2;
  u16* wdT = (u16*)w;           // NEXP*HID*FFN*2

  hipMemsetAsync(d_out, 0, (size_t)T_TOK*HID*4, stream);
  hipMemsetAsync(counts, 0, 256, stream);

  k_prep_x<<<2048, 256, 0, stream>>>(x, xh, xl, T_TOK*HID/8);
  k_prep_gate<<<NPAD, 256, 0, stream>>>(gate_w, gh, gl);
  k_router<<<T_TOK/64, 256, 0, stream>>>(xh, xl, gh, gl, logits_out, tk_idx, tk_w, counts);
  k_scan<<<1, 64, 0, stream>>>(counts, offsets, cursors);
  k_build<<<T_TOK/256, 256, 0, stream>>>(tk_idx, tk_w, cursors, rows, rwgt);

  // one-shot full weight conversion to bf16 [n][k]
  k_convT<<<dim3(FFN/64, HID/128, NEXP), 256, 0, stream>>>(wg, wgT, HID, FFN);
  k_convT<<<dim3(FFN/64, HID/128, NEXP), 256, 0, stream>>>(wu, wuT, HID, FFN);
  k_convT<<<dim3(HID/64, FFN/128, NEXP), 256, 0, stream>>>(wd, wdT, FFN, HID);

  // gate writes G into inter; up reads G and overwrites with silu(G)*U
  k_gate<<<4096, 256, 0, stream>>>(xh, wgT, counts, offsets, rows, inter);
  k_up<<<4096, 256, 0, stream>>>(xh, wuT, counts, offsets, rows, inter);
  k_expert_down<<<4096, 256, 0, stream>>>(inter, wdT, counts, offsets, rows, rwgt, out);
}